// Round 3
// baseline (767.184 us; speedup 1.0000x reference)
//
#include <hip/hip_runtime.h>
#include <hip/hip_bf16.h>
#include <stdint.h>

#define NATOMS 200000
#define NBONDS 300000
#define NEDGE  600000
#define NSEG   (NATOMS + NBONDS)   // 500000 combined dst rows
#define DF     128
#define EPS    1e-5f
#define SCHUNK 2048
#define NSBLK  ((NSEG + SCHUNK - 1) / SCHUNK)  // 245
#define NCHA   (NATOMS / 64)            // 3125 (exact)
#define NCHB   ((NBONDS + 63) / 64)     // 4688
#define NCH    (NCHA + NCHB)            // 7813

typedef __attribute__((ext_vector_type(8))) short bf16x8;
typedef __attribute__((ext_vector_type(4))) float f32x4;
typedef unsigned short u16;

__device__ __forceinline__ short f2b(float f) {
  union { float f; uint32_t u; } v; v.f = f;
  uint32_t r = v.u + 0x7fffu + ((v.u >> 16) & 1u);
  return (short)(r >> 16);
}
__device__ __forceinline__ float bf2f(u16 h) {
  union { uint32_t u; float f; } v; v.u = ((uint32_t)h) << 16; return v.f;
}
__device__ __forceinline__ bf16x8 zero8() {
  bf16x8 z;
#pragma unroll
  for (int i = 0; i < 8; ++i) z[i] = 0;
  return z;
}

// ---- convert weights to bf16 ----
__global__ void k_prep(const float* __restrict__ W, const float* __restrict__ Wr,
                       u16* __restrict__ Wb, u16* __restrict__ Wrb) {
  int i = blockIdx.x * blockDim.x + threadIdx.x;
  if (i < DF * DF) {
    Wb[i]  = (u16)f2b(W[i]);
    Wrb[i] = (u16)f2b(Wr[i]);
  }
}

// ---- convert x to bf16 (tier A) ----
__global__ void k_conv(const float* __restrict__ x, u16* __restrict__ xT, int n8) {
  int stride = gridDim.x * blockDim.x;
  for (int i = blockIdx.x * blockDim.x + threadIdx.x; i < n8; i += stride) {
    const float4 a = *(const float4*)(x + (size_t)i * 8);
    const float4 b = *(const float4*)(x + (size_t)i * 8 + 4);
    bf16x8 r;
    r[0] = f2b(a.x); r[1] = f2b(a.y); r[2] = f2b(a.z); r[3] = f2b(a.w);
    r[4] = f2b(b.x); r[5] = f2b(b.y); r[6] = f2b(b.z); r[7] = f2b(b.w);
    *(bf16x8*)(xT + (size_t)i * 8) = r;
  }
}

// ---- histogram of combined dst indices ----
__global__ void k_hist(const int* __restrict__ ab, const int* __restrict__ ba,
                       int* __restrict__ cnt) {
  int stride = gridDim.x * blockDim.x;
  for (int e = blockIdx.x * blockDim.x + threadIdx.x; e < 2 * NEDGE; e += stride) {
    int g;
    if (e < NEDGE) g = NATOMS + ab[NEDGE + e];
    else           g = ba[NEDGE + (e - NEDGE)];
    atomicAdd(cnt + g, 1);
  }
}

// ---- 3-phase exclusive scan ----
__global__ void k_scanA(const int* __restrict__ cnt, int* __restrict__ bsum) {
  __shared__ int wsm[4];
  int t = threadIdx.x;
  int base = blockIdx.x * SCHUNK + t * 8;
  int s = 0;
#pragma unroll
  for (int j = 0; j < 8; ++j) { int i = base + j; if (i < NSEG) s += cnt[i]; }
  for (int d = 1; d < 64; d <<= 1) s += __shfl_xor(s, d);
  if ((t & 63) == 0) wsm[t >> 6] = s;
  __syncthreads();
  if (t == 0) bsum[blockIdx.x] = wsm[0] + wsm[1] + wsm[2] + wsm[3];
}

__global__ void k_scanB(const int* __restrict__ bsum, int* __restrict__ bbase) {
  __shared__ int wsm[4];
  int t = threadIdx.x;
  int lane = t & 63;
  int v = (t < NSBLK) ? bsum[t] : 0;
  int s = v;
  for (int d = 1; d < 64; d <<= 1) { int n = __shfl_up(s, d); if (lane >= d) s += n; }
  if (lane == 63) wsm[t >> 6] = s;
  __syncthreads();
  int wbase = 0;
  for (int w = 0; w < (t >> 6); ++w) wbase += wsm[w];
  if (t < NSBLK) bbase[t] = wbase + s - v;
}

__global__ void k_scanC(const int* __restrict__ cnt, const int* __restrict__ bbase,
                        int* __restrict__ off, int* __restrict__ cursor) {
  __shared__ int wsm[4];
  int t = threadIdx.x;
  int lane = t & 63, wv = t >> 6;
  int base = blockIdx.x * SCHUNK + t * 8;
  int v[8]; int ts = 0;
#pragma unroll
  for (int j = 0; j < 8; ++j) { int i = base + j; v[j] = (i < NSEG) ? cnt[i] : 0; ts += v[j]; }
  int s = ts;
  for (int d = 1; d < 64; d <<= 1) { int n = __shfl_up(s, d); if (lane >= d) s += n; }
  if (lane == 63) wsm[wv] = s;
  __syncthreads();
  int wbase = bbase[blockIdx.x];
  for (int w = 0; w < wv; ++w) wbase += wsm[w];
  int run = wbase + s - ts;
#pragma unroll
  for (int j = 0; j < 8; ++j) {
    int i = base + j;
    if (i < NSEG) { off[i] = run; cursor[i] = run; }
    run += v[j];
  }
}

// ---- bucket src indices per dst ----
__global__ void k_fill(const int* __restrict__ ab, const int* __restrict__ ba,
                       int* __restrict__ cursor, int* __restrict__ sorted) {
  int stride = gridDim.x * blockDim.x;
  for (int e = blockIdx.x * blockDim.x + threadIdx.x; e < 2 * NEDGE; e += stride) {
    int g, src;
    if (e < NEDGE) { g = NATOMS + ab[NEDGE + e]; src = ab[e]; }
    else { int e2 = e - NEDGE; g = ba[NEDGE + e2]; src = ba[e2]; }
    int pos = atomicAdd(cursor + g, 1);
    sorted[pos] = src;
  }
}

// ---- gather-sum ----
template<int LP>
__global__ void k_gather(const float* __restrict__ xa, const float* __restrict__ xb,
                         const u16* __restrict__ xaT, const u16* __restrict__ xbT,
                         const int* __restrict__ sorted, const int* __restrict__ off,
                         const int* __restrict__ cnt,
                         float* __restrict__ outf, u16* __restrict__ aggT) {
  if constexpr (LP) {
    // quarter-wave per dst row: 16 lanes x bf16x8 = 256B row
    int lane = threadIdx.x & 63;
    int q = lane >> 4, l16 = lane & 15;
    int wid = (blockIdx.x * blockDim.x + threadIdx.x) >> 6;
    int nw = (gridDim.x * blockDim.x) >> 6;
    for (int base = wid * 4; base < NSEG; base += nw * 4) {
      int g = base + q;   // NSEG % 4 == 0, always valid
      int start = off[g], deg = cnt[g];
      const u16* src = (g < NATOMS) ? xbT : xaT;
      float acc[8];
#pragma unroll
      for (int j = 0; j < 8; ++j) acc[j] = 0.f;
      int k = 0;
      for (; k + 1 < deg; k += 2) {
        int s0 = sorted[start + k], s1 = sorted[start + k + 1];
        bf16x8 v0 = *(const bf16x8*)(src + (size_t)s0 * DF + l16 * 8);
        bf16x8 v1 = *(const bf16x8*)(src + (size_t)s1 * DF + l16 * 8);
#pragma unroll
        for (int j = 0; j < 8; ++j) acc[j] += bf2f((u16)v0[j]) + bf2f((u16)v1[j]);
      }
      if (k < deg) {
        int s0 = sorted[start + k];
        bf16x8 v0 = *(const bf16x8*)(src + (size_t)s0 * DF + l16 * 8);
#pragma unroll
        for (int j = 0; j < 8; ++j) acc[j] += bf2f((u16)v0[j]);
      }
      bf16x8 r;
#pragma unroll
      for (int j = 0; j < 8; ++j) r[j] = f2b(acc[j]);
      *(bf16x8*)(aggT + (size_t)g * DF + l16 * 8) = r;
    }
  } else {
    // wave per dst row, fp32, writes into outf
    int wid = (blockIdx.x * blockDim.x + threadIdx.x) >> 6;
    int lane = threadIdx.x & 63;
    int nw = (gridDim.x * blockDim.x) >> 6;
    for (int g = wid; g < NSEG; g += nw) {
      int start = off[g], deg = cnt[g];
      const float* src = (g < NATOMS) ? xb : xa;
      float ax = 0.f, ay = 0.f;
      int k = 0;
      for (; k + 1 < deg; k += 2) {
        int s0 = sorted[start + k], s1 = sorted[start + k + 1];
        float2 v0 = *(const float2*)(src + (size_t)s0 * DF + lane * 2);
        float2 v1 = *(const float2*)(src + (size_t)s1 * DF + lane * 2);
        ax += v0.x + v1.x; ay += v0.y + v1.y;
      }
      if (k < deg) {
        int s0 = sorted[start + k];
        float2 v0 = *(const float2*)(src + (size_t)s0 * DF + lane * 2);
        ax += v0.x; ay += v0.y;
      }
      float2 r; r.x = ax; r.y = ay;
      *(float2*)(outf + (size_t)g * DF + lane * 2) = r;
    }
  }
}

// ---- persistent fused GEMM: g = agg@W^T + cnt*b + relu(x@Wr^T + br); BN partials ----
template<int LP>
__global__ __launch_bounds__(256, 2) void k_gemm(
    const float* __restrict__ xa, const float* __restrict__ xb,
    const u16* __restrict__ xaT, const u16* __restrict__ xbT,
    const u16* __restrict__ aggT, u16* __restrict__ gT,
    float* __restrict__ outf,
    const int* __restrict__ cnt,
    const u16* __restrict__ Wb, const u16* __restrict__ Wrb,
    const float* __restrict__ bb, const float* __restrict__ brb,
    float* __restrict__ stats) {
  __shared__ u16 Wl[DF * DF];    // 32KB, XOR-swizzled
  __shared__ u16 Wrl[DF * DF];   // 32KB
  __shared__ float red[4 * DF];  // 2KB BN scratch

  {
    const uint4* gw  = (const uint4*)Wb;
    const uint4* gwr = (const uint4*)Wrb;
    uint4* lw  = (uint4*)Wl;
    uint4* lwr = (uint4*)Wrl;
    for (int i = threadIdx.x; i < DF * DF / 8; i += 256) {
      int row = i >> 4, c8 = i & 15;
      int dst = (row << 4) | (c8 ^ (row & 7));
      lw[dst]  = gw[i];
      lwr[dst] = gwr[i];
    }
  }
  __syncthreads();

  int lane = threadIdx.x & 63;
  int wv = threadIdx.x >> 6;
  int r16 = lane & 15, kq = lane >> 4;

  float bvv[8], brr[8];
#pragma unroll
  for (int t = 0; t < 8; ++t) { bvv[t] = bb[t * 16 + r16]; brr[t] = brb[t * 16 + r16]; }

  float lsA[8], lqA[8], lsB[8], lqB[8];
#pragma unroll
  for (int t = 0; t < 8; ++t) { lsA[t] = 0.f; lqA[t] = 0.f; lsB[t] = 0.f; lqB[t] = 0.f; }

  auto geomf = [&](int c, int& typ, int& nrows, int& goff, int& arow, bool& av) {
    if (c < NCHA) { typ = 0; nrows = NATOMS; goff = 0; arow = c * 64 + wv * 16 + r16; }
    else { typ = 1; nrows = NBONDS; goff = NATOMS; arow = (c - NCHA) * 64 + wv * 16 + r16; }
    av = arow < nrows;
  };

  auto loadf = [&](int typ, int goff, int arow, bool av, bf16x8* fA, bf16x8* fX) {
    const u16* ap = aggT + (size_t)(goff + arow) * DF + kq * 8;
    const u16* xp = (typ ? xbT : xaT) + (size_t)arow * DF + kq * 8;
#pragma unroll
    for (int kk = 0; kk < 4; ++kk) {
      fA[kk] = av ? *(const bf16x8*)(ap + kk * 32) : zero8();
      fX[kk] = av ? *(const bf16x8*)(xp + kk * 32) : zero8();
    }
  };

  auto compute = [&](int typ, int nrows, int goff, int arow,
                     const bf16x8* fA, const bf16x8* fX) {
    f32x4 accW[8], accR[8];
#pragma unroll
    for (int t = 0; t < 8; ++t) {
#pragma unroll
      for (int r = 0; r < 4; ++r) { accW[t][r] = 0.f; accR[t][r] = 0.f; }
    }
#pragma unroll
    for (int kk = 0; kk < 4; ++kk) {
      int c8 = kk * 4 + kq;
#pragma unroll
      for (int t = 0; t < 8; ++t) {
        int rw = t * 16 + r16;
        int chunk = (rw << 4) | (c8 ^ (rw & 7));
        bf16x8 bW = *(const bf16x8*)(Wl + chunk * 8);
        bf16x8 bR = *(const bf16x8*)(Wrl + chunk * 8);
        accW[t] = __builtin_amdgcn_mfma_f32_16x16x32_bf16(fA[kk], bW, accW[t], 0, 0, 0);
        accR[t] = __builtin_amdgcn_mfma_f32_16x16x32_bf16(fX[kk], bR, accR[t], 0, 0, 0);
      }
    }
    // C/D layout: col = lane&15, row = (lane>>4)*4 + reg  [m89-verified]
    int orow0 = (arow - r16) + kq * 4;
    const int* cp = cnt + goff;
    float cf[4];
#pragma unroll
    for (int r = 0; r < 4; ++r) {
      int rr = orow0 + r;
      cf[r] = (rr < nrows) ? (float)cp[rr] : 0.f;
    }
    float ts[8], tq[8];
#pragma unroll
    for (int t = 0; t < 8; ++t) {
      int feat = t * 16 + r16;
      float s = 0.f, q2 = 0.f;
#pragma unroll
      for (int r = 0; r < 4; ++r) {
        int rr = orow0 + r;
        if (rr < nrows) {
          float gg = accW[t][r] + cf[r] * bvv[t] + fmaxf(accR[t][r] + brr[t], 0.f);
          if constexpr (LP) gT[(size_t)(goff + rr) * DF + feat] = (u16)f2b(gg);
          else              outf[(size_t)(goff + rr) * DF + feat] = gg;
          s += gg; q2 += gg * gg;
        }
      }
      ts[t] = s; tq[t] = q2;
    }
    if (typ == 0) {
#pragma unroll
      for (int t = 0; t < 8; ++t) { lsA[t] += ts[t]; lqA[t] += tq[t]; }
    } else {
#pragma unroll
      for (int t = 0; t < 8; ++t) { lsB[t] += ts[t]; lqB[t] += tq[t]; }
    }
  };

  if constexpr (LP) {
    // pipelined: issue next chunk's fragment loads before current chunk's MFMAs
    int c = blockIdx.x;
    int ctyp = 0, cnr = 0, cgo = 0, car = 0; bool cav = false;
    bf16x8 cA[4], cX[4];
    if (c < NCH) { geomf(c, ctyp, cnr, cgo, car, cav); loadf(ctyp, cgo, car, cav, cA, cX); }
    while (c < NCH) {
      int cn = c + gridDim.x;
      int ntyp = 0, nnr = 0, ngo = 0, nar = 0; bool nav = false;
      bf16x8 nA[4], nX[4];
      if (cn < NCH) { geomf(cn, ntyp, nnr, ngo, nar, nav); loadf(ntyp, ngo, nar, nav, nA, nX); }
      compute(ctyp, cnr, cgo, car, cA, cX);
      c = cn;
      if (c < NCH) {
        ctyp = ntyp; cnr = nnr; cgo = ngo; car = nar; cav = nav;
#pragma unroll
        for (int kk = 0; kk < 4; ++kk) { cA[kk] = nA[kk]; cX[kk] = nX[kk]; }
      }
    }
  } else {
    for (int c = blockIdx.x; c < NCH; c += gridDim.x) {
      int typ, nr, go, ar; bool av;
      geomf(c, typ, nr, go, ar, av);
      bf16x8 fA[4], fX[4];
      const float* ap = outf + (size_t)(go + ar) * DF + kq * 8;
      const float* xp = (typ ? xb : xa) + (size_t)ar * DF + kq * 8;
#pragma unroll
      for (int kk = 0; kk < 4; ++kk) {
        if (av) {
          float4 a0 = *(const float4*)(ap + kk * 32);
          float4 a1 = *(const float4*)(ap + kk * 32 + 4);
          float4 x0 = *(const float4*)(xp + kk * 32);
          float4 x1 = *(const float4*)(xp + kk * 32 + 4);
          bf16x8 A, X;
          A[0] = f2b(a0.x); A[1] = f2b(a0.y); A[2] = f2b(a0.z); A[3] = f2b(a0.w);
          A[4] = f2b(a1.x); A[5] = f2b(a1.y); A[6] = f2b(a1.z); A[7] = f2b(a1.w);
          X[0] = f2b(x0.x); X[1] = f2b(x0.y); X[2] = f2b(x0.z); X[3] = f2b(x0.w);
          X[4] = f2b(x1.x); X[5] = f2b(x1.y); X[6] = f2b(x1.z); X[7] = f2b(x1.w);
          fA[kk] = A; fX[kk] = X;
        } else { fA[kk] = zero8(); fX[kk] = zero8(); }
      }
      compute(typ, nr, go, ar, fA, fX);
    }
  }

  // block-level BN reduction (weights LDS no longer needed)
  __syncthreads();
  if (threadIdx.x < 256) { red[threadIdx.x] = 0.f; red[256 + threadIdx.x] = 0.f; }
  __syncthreads();
#pragma unroll
  for (int t = 0; t < 8; ++t) {
    float s0 = lsA[t], q0 = lqA[t], s1 = lsB[t], q1 = lqB[t];
    s0 += __shfl_xor(s0, 16); q0 += __shfl_xor(q0, 16);
    s1 += __shfl_xor(s1, 16); q1 += __shfl_xor(q1, 16);
    s0 += __shfl_xor(s0, 32); q0 += __shfl_xor(q0, 32);
    s1 += __shfl_xor(s1, 32); q1 += __shfl_xor(q1, 32);
    if (kq == 0) {
      int f = t * 16 + r16;
      atomicAdd(&red[f], s0);          atomicAdd(&red[DF + f], q0);
      atomicAdd(&red[2 * DF + f], s1); atomicAdd(&red[3 * DF + f], q1);
    }
  }
  __syncthreads();
  if (threadIdx.x < 256) {
    atomicAdd(&stats[threadIdx.x], red[threadIdx.x]);
    atomicAdd(&stats[256 + threadIdx.x], red[256 + threadIdx.x]);
  }
}

// ---- finalize stats -> scale/shift per (type, feature) ----
__global__ void k_stats(const float* __restrict__ stats,
                        const float* __restrict__ ga, const float* __restrict__ bea,
                        const float* __restrict__ gb, const float* __restrict__ beb,
                        float* __restrict__ scale, float* __restrict__ shift) {
  int tid = threadIdx.x;
  if (tid < 2 * DF) {
    int t = tid >> 7, f = tid & (DF - 1);
    float S  = stats[t * 256 + f];
    float SS = stats[t * 256 + DF + f];
    float n = t ? (float)NBONDS : (float)NATOMS;
    float mean = S / n;
    float var = SS / n - mean * mean;
    float rstd = rsqrtf(var + EPS);
    float g = t ? gb[f] : ga[f];
    float be = t ? beb[f] : bea[f];
    scale[tid] = rstd * g;
    shift[tid] = be - mean * rstd * g;
  }
}

// ---- normalize ----
template<int LP>
__global__ void k_norm(float* __restrict__ out, const u16* __restrict__ gT,
                       const float* __restrict__ scale, const float* __restrict__ shift) {
  if constexpr (LP) {
    const size_t nv = (size_t)NSEG * DF / 8;
    size_t stride = (size_t)gridDim.x * blockDim.x;
    for (size_t i = (size_t)blockIdx.x * blockDim.x + threadIdx.x; i < nv; i += stride) {
      size_t e = i * 8;
      int t = e >= (size_t)NATOMS * DF;
      int f = (int)(e & (DF - 1));
      bf16x8 v = *(const bf16x8*)(gT + e);
      const float* sc = scale + t * DF + f;
      const float* sh = shift + t * DF + f;
      float4 o0, o1;
      o0.x = fmaf(bf2f((u16)v[0]), sc[0], sh[0]);
      o0.y = fmaf(bf2f((u16)v[1]), sc[1], sh[1]);
      o0.z = fmaf(bf2f((u16)v[2]), sc[2], sh[2]);
      o0.w = fmaf(bf2f((u16)v[3]), sc[3], sh[3]);
      o1.x = fmaf(bf2f((u16)v[4]), sc[4], sh[4]);
      o1.y = fmaf(bf2f((u16)v[5]), sc[5], sh[5]);
      o1.z = fmaf(bf2f((u16)v[6]), sc[6], sh[6]);
      o1.w = fmaf(bf2f((u16)v[7]), sc[7], sh[7]);
      *(float4*)(out + e) = o0;
      *(float4*)(out + e + 4) = o1;
    }
  } else {
    const size_t nv = (size_t)NSEG * DF / 4;
    size_t stride = (size_t)gridDim.x * blockDim.x;
    for (size_t i = (size_t)blockIdx.x * blockDim.x + threadIdx.x; i < nv; i += stride) {
      size_t e = i * 4;
      int t = e >= (size_t)NATOMS * DF;
      int f = (int)(e & (DF - 1));
      const float* sc = scale + t * DF + f;
      const float* sh = shift + t * DF + f;
      float4 v = ((float4*)out)[i];
      v.x = fmaf(v.x, sc[0], sh[0]);
      v.y = fmaf(v.y, sc[1], sh[1]);
      v.z = fmaf(v.z, sc[2], sh[2]);
      v.w = fmaf(v.w, sc[3], sh[3]);
      ((float4*)out)[i] = v;
    }
  }
}

extern "C" void kernel_launch(void* const* d_in, const int* in_sizes, int n_in,
                              void* d_out, int out_size, void* d_ws, size_t ws_size,
                              hipStream_t stream) {
  const float* xa  = (const float*)d_in[0];
  const float* xb  = (const float*)d_in[1];
  const int*   ab  = (const int*)d_in[2];
  const int*   ba  = (const int*)d_in[3];
  const float* W   = (const float*)d_in[4];
  const float* b   = (const float*)d_in[5];
  const float* Wr  = (const float*)d_in[6];
  const float* br  = (const float*)d_in[7];
  const float* ga  = (const float*)d_in[8];
  const float* bea = (const float*)d_in[9];
  const float* gb  = (const float*)d_in[10];
  const float* beb = (const float*)d_in[11];
  float* out = (float*)d_out;

  char* ws = (char*)d_ws;
  int*   cnt    = (int*)ws;                     // 2,000,000
  int*   off    = (int*)(ws +  2000000);        // 2,000,000
  int*   cursor = (int*)(ws +  4000000);        // 2,000,000
  int*   sorted = (int*)(ws +  6000000);        // 4,800,000
  float* stats  = (float*)(ws + 10800000);      // 2,048
  u16*   Wbf    = (u16*)(ws + 10802048);        // 32,768
  u16*   Wrbf   = (u16*)(ws + 10834816);        // 32,768
  float* scale  = (float*)(ws + 10867584);      // 1,024
  float* shift  = (float*)(ws + 10868608);      // 1,024
  int*   bsum   = (int*)(ws + 10869632);        // 1,024
  int*   bbase  = (int*)(ws + 10870656);        // 1,024
  // tier A (bf16) buffers, 16B-aligned offsets
  u16*   xaT  = (u16*)(ws +  10871680);         // 51,200,000
  u16*   xbT  = (u16*)(ws +  62071680);         // 76,800,000
  u16*   aggT = (u16*)(ws + 138871680);         // 128,000,000
  u16*   gT   = (u16*)(ws + 266871680);         // 128,000,000
  const bool lp = ws_size >= 394871680ull;

  hipMemsetAsync(cnt, 0, 2000000, stream);
  hipMemsetAsync(stats, 0, 2048, stream);

  k_prep<<<64, 256, 0, stream>>>(W, Wr, Wbf, Wrbf);
  if (lp) {
    k_conv<<<2048, 256, 0, stream>>>(xa, xaT, NATOMS * DF / 8);
    k_conv<<<2048, 256, 0, stream>>>(xb, xbT, NBONDS * DF / 8);
  }
  k_hist<<<2048, 256, 0, stream>>>(ab, ba, cnt);
  k_scanA<<<NSBLK, 256, 0, stream>>>(cnt, bsum);
  k_scanB<<<1, 256, 0, stream>>>(bsum, bbase);
  k_scanC<<<NSBLK, 256, 0, stream>>>(cnt, bbase, off, cursor);
  k_fill<<<2048, 256, 0, stream>>>(ab, ba, cursor, sorted);
  if (lp) {
    k_gather<1><<<4096, 256, 0, stream>>>(xa, xb, xaT, xbT, sorted, off, cnt, out, aggT);
    k_gemm<1><<<512, 256, 0, stream>>>(xa, xb, xaT, xbT, aggT, gT, out, cnt,
                                       Wbf, Wrbf, b, br, stats);
  } else {
    k_gather<0><<<8192, 256, 0, stream>>>(xa, xb, xaT, xbT, sorted, off, cnt, out, aggT);
    k_gemm<0><<<512, 256, 0, stream>>>(xa, xb, xaT, xbT, aggT, gT, out, cnt,
                                       Wbf, Wrbf, b, br, stats);
  }
  k_stats<<<1, 256, 0, stream>>>(stats, ga, bea, gb, beb, scale, shift);
  if (lp) k_norm<1><<<4096, 256, 0, stream>>>(out, gT, scale, shift);
  else    k_norm<0><<<16384, 256, 0, stream>>>(out, gT, scale, shift);
}

// Round 4
// 611.834 us; speedup vs baseline: 1.2539x; 1.2539x over previous
//
#include <hip/hip_runtime.h>
#include <stdint.h>

#define NATOMS 200000
#define NBONDS 300000
#define NEDGE  600000
#define NSEG   (NATOMS + NBONDS)   // 500000
#define DF     128
#define EPS    1e-5f
#define SCHUNK 2048
#define NSBLK  ((NSEG + SCHUNK - 1) / SCHUNK)  // 245
#define NCHA   (NATOMS / 64)            // 3125 exact
#define NCHB   ((NBONDS + 63) / 64)     // 4688 (tail 32 rows = 2 full 16-row groups)
#define NCH    (NCHA + NCHB)            // 7813
#define NBUCK  32

typedef __attribute__((ext_vector_type(8))) short bf16x8;
typedef __attribute__((ext_vector_type(4))) float f32x4;
typedef unsigned short u16;
typedef __attribute__((ext_vector_type(4))) unsigned short u16x4;

__device__ __forceinline__ short f2b(float f) {
  union { float f; uint32_t u; } v; v.f = f;
  uint32_t r = v.u + 0x7fffu + ((v.u >> 16) & 1u);
  return (short)(r >> 16);
}
__device__ __forceinline__ float bf2f(u16 h) {
  union { uint32_t u; float f; } v; v.u = ((uint32_t)h) << 16; return v.f;
}
__device__ __forceinline__ bf16x8 pack8(float4 u, float4 v) {
  bf16x8 t;
  t[0] = f2b(u.x); t[1] = f2b(u.y); t[2] = f2b(u.z); t[3] = f2b(u.w);
  t[4] = f2b(v.x); t[5] = f2b(v.y); t[6] = f2b(v.z); t[7] = f2b(v.w);
  return t;
}

// ---- weights -> bf16 ----
__global__ void k_prep(const float* __restrict__ W, const float* __restrict__ Wr,
                       u16* __restrict__ Wb, u16* __restrict__ Wrb) {
  int i = blockIdx.x * blockDim.x + threadIdx.x;
  if (i < DF * DF) {
    Wb[i]  = (u16)f2b(W[i]);
    Wrb[i] = (u16)f2b(Wr[i]);
  }
}

// ---- x -> bf16 (XT tier) ----
__global__ void k_conv(const float* __restrict__ x, u16* __restrict__ xT, int n8) {
  int stride = gridDim.x * blockDim.x;
  for (int i = blockIdx.x * blockDim.x + threadIdx.x; i < n8; i += stride) {
    const float4 a = *(const float4*)(x + (size_t)i * 8);
    const float4 b = *(const float4*)(x + (size_t)i * 8 + 4);
    *(bf16x8*)(xT + (size_t)i * 8) = pack8(a, b);
  }
}

// ---- histogram of combined dst indices ----
__global__ void k_hist(const int* __restrict__ ab, const int* __restrict__ ba,
                       int* __restrict__ cnt) {
  int stride = gridDim.x * blockDim.x;
  for (int e = blockIdx.x * blockDim.x + threadIdx.x; e < 2 * NEDGE; e += stride) {
    int g;
    if (e < NEDGE) g = NATOMS + ab[NEDGE + e];
    else           g = ba[NEDGE + (e - NEDGE)];
    atomicAdd(cnt + g, 1);
  }
}

// ---- 3-phase exclusive scan ----
__global__ void k_scanA(const int* __restrict__ cnt, int* __restrict__ bsum) {
  __shared__ int wsm[4];
  int t = threadIdx.x;
  int base = blockIdx.x * SCHUNK + t * 8;
  int s = 0;
#pragma unroll
  for (int j = 0; j < 8; ++j) { int i = base + j; if (i < NSEG) s += cnt[i]; }
  for (int d = 1; d < 64; d <<= 1) s += __shfl_xor(s, d);
  if ((t & 63) == 0) wsm[t >> 6] = s;
  __syncthreads();
  if (t == 0) bsum[blockIdx.x] = wsm[0] + wsm[1] + wsm[2] + wsm[3];
}

__global__ void k_scanB(const int* __restrict__ bsum, int* __restrict__ bbase) {
  __shared__ int wsm[4];
  int t = threadIdx.x;
  int lane = t & 63;
  int v = (t < NSBLK) ? bsum[t] : 0;
  int s = v;
  for (int d = 1; d < 64; d <<= 1) { int n = __shfl_up(s, d); if (lane >= d) s += n; }
  if (lane == 63) wsm[t >> 6] = s;
  __syncthreads();
  int wbase = 0;
  for (int w = 0; w < (t >> 6); ++w) wbase += wsm[w];
  if (t < NSBLK) bbase[t] = wbase + s - v;
}

__global__ void k_scanC(const int* __restrict__ cnt, const int* __restrict__ bbase,
                        int* __restrict__ off, int* __restrict__ cursor) {
  __shared__ int wsm[4];
  int t = threadIdx.x;
  int lane = t & 63, wv = t >> 6;
  int base = blockIdx.x * SCHUNK + t * 8;
  int v[8]; int ts = 0;
#pragma unroll
  for (int j = 0; j < 8; ++j) { int i = base + j; v[j] = (i < NSEG) ? cnt[i] : 0; ts += v[j]; }
  int s = ts;
  for (int d = 1; d < 64; d <<= 1) { int n = __shfl_up(s, d); if (lane >= d) s += n; }
  if (lane == 63) wsm[wv] = s;
  __syncthreads();
  int wbase = bbase[blockIdx.x];
  for (int w = 0; w < wv; ++w) wbase += wsm[w];
  int run = wbase + s - ts;
#pragma unroll
  for (int j = 0; j < 8; ++j) {
    int i = base + j;
    if (i < NSEG) { off[i] = run; cursor[i] = run; }
    run += v[j];
  }
}

// ---- bucket src indices per dst ----
__global__ void k_fill(const int* __restrict__ ab, const int* __restrict__ ba,
                       int* __restrict__ cursor, int* __restrict__ sorted) {
  int stride = gridDim.x * blockDim.x;
  for (int e = blockIdx.x * blockDim.x + threadIdx.x; e < 2 * NEDGE; e += stride) {
    int g, src;
    if (e < NEDGE) { g = NATOMS + ab[NEDGE + e]; src = ab[e]; }
    else { int e2 = e - NEDGE; g = ba[NEDGE + e2]; src = ba[e2]; }
    int pos = atomicAdd(cursor + g, 1);
    sorted[pos] = src;
  }
}

// ---- gather-sum: half-wave (32 lanes) per dst row ----
template<int AGG, int XT>
__global__ void k_gather(const float* __restrict__ xa, const float* __restrict__ xb,
                         const u16* __restrict__ xaT, const u16* __restrict__ xbT,
                         const int* __restrict__ sorted, const int* __restrict__ off,
                         const int* __restrict__ cnt,
                         float* __restrict__ outf, u16* __restrict__ aggT) {
  int l32 = threadIdx.x & 31;
  int hwid = (blockIdx.x * blockDim.x + threadIdx.x) >> 5;
  int nhw = (gridDim.x * blockDim.x) >> 5;
  for (int g = hwid; g < NSEG; g += nhw) {
    int start = off[g], deg = cnt[g];
    float a0 = 0.f, a1 = 0.f, a2 = 0.f, a3 = 0.f;
    if constexpr (XT) {
      const u16* src = (g < NATOMS) ? xbT : xaT;
      int k = 0;
      for (; k + 1 < deg; k += 2) {
        int s0 = sorted[start + k], s1 = sorted[start + k + 1];
        u16x4 v0 = *(const u16x4*)(src + (size_t)s0 * DF + l32 * 4);
        u16x4 v1 = *(const u16x4*)(src + (size_t)s1 * DF + l32 * 4);
        a0 += bf2f(v0[0]) + bf2f(v1[0]);
        a1 += bf2f(v0[1]) + bf2f(v1[1]);
        a2 += bf2f(v0[2]) + bf2f(v1[2]);
        a3 += bf2f(v0[3]) + bf2f(v1[3]);
      }
      if (k < deg) {
        int s0 = sorted[start + k];
        u16x4 v0 = *(const u16x4*)(src + (size_t)s0 * DF + l32 * 4);
        a0 += bf2f(v0[0]); a1 += bf2f(v0[1]); a2 += bf2f(v0[2]); a3 += bf2f(v0[3]);
      }
    } else {
      const float* src = (g < NATOMS) ? xb : xa;
      int k = 0;
      for (; k + 1 < deg; k += 2) {
        int s0 = sorted[start + k], s1 = sorted[start + k + 1];
        float4 v0 = *(const float4*)(src + (size_t)s0 * DF + l32 * 4);
        float4 v1 = *(const float4*)(src + (size_t)s1 * DF + l32 * 4);
        a0 += v0.x + v1.x; a1 += v0.y + v1.y; a2 += v0.z + v1.z; a3 += v0.w + v1.w;
      }
      if (k < deg) {
        int s0 = sorted[start + k];
        float4 v0 = *(const float4*)(src + (size_t)s0 * DF + l32 * 4);
        a0 += v0.x; a1 += v0.y; a2 += v0.z; a3 += v0.w;
      }
    }
    if constexpr (AGG) {
      u16x4 r;
      r[0] = (u16)f2b(a0); r[1] = (u16)f2b(a1); r[2] = (u16)f2b(a2); r[3] = (u16)f2b(a3);
      *(u16x4*)(aggT + (size_t)g * DF + l32 * 4) = r;
    } else {
      float4 r; r.x = a0; r.y = a1; r.z = a2; r.w = a3;
      *(float4*)(outf + (size_t)g * DF + l32 * 4) = r;
    }
  }
}

// ---- register-weight fused GEMM: g = agg@W^T + cnt*b + relu(x@Wr^T + br) ----
// No LDS, no barriers. Wave wv owns features [wv*32, wv*32+32) (2 column tiles).
template<int AGG, int XT>
__global__ __launch_bounds__(256, 3) void k_gemm(
    const float* __restrict__ xa, const float* __restrict__ xb,
    const u16* __restrict__ xaT, const u16* __restrict__ xbT,
    const u16* __restrict__ aggT, float* __restrict__ outf,
    const int* __restrict__ cnt,
    const u16* __restrict__ Wb, const u16* __restrict__ Wrb,
    const float* __restrict__ bb, const float* __restrict__ brb,
    float* __restrict__ stats) {
  int lane = threadIdx.x & 63;
  int wv = threadIdx.x >> 6;        // 0..3 -> feature block
  int r16 = lane & 15, kq = lane >> 4;
  int t0 = wv * 2;

  // B-fragments (W, Wr) live in registers for the whole kernel.
  // B-frag for tile(t,kk): lane holds W[t*16 + r16][kk*32 + kq*8 + j], j=0..7
  bf16x8 wf[2][4], wrf[2][4];
#pragma unroll
  for (int ti = 0; ti < 2; ++ti) {
#pragma unroll
    for (int kk = 0; kk < 4; ++kk) {
      size_t o = (size_t)((t0 + ti) * 16 + r16) * DF + kk * 32 + kq * 8;
      wf[ti][kk]  = *(const bf16x8*)(Wb + o);
      wrf[ti][kk] = *(const bf16x8*)(Wrb + o);
    }
  }
  float bvv[2], brr[2];
#pragma unroll
  for (int ti = 0; ti < 2; ++ti) {
    bvv[ti] = bb[(t0 + ti) * 16 + r16];
    brr[ti] = brb[(t0 + ti) * 16 + r16];
  }

  float sA[2] = {0.f, 0.f}, qA[2] = {0.f, 0.f};
  float sB[2] = {0.f, 0.f}, qB[2] = {0.f, 0.f};

  for (int c = blockIdx.x; c < NCH; c += gridDim.x) {
    int typ, nrows, goff, base;
    if (c < NCHA) { typ = 0; nrows = NATOMS; goff = 0; base = c * 64; }
    else { typ = 1; nrows = NBONDS; goff = NATOMS; base = (c - NCHA) * 64; }
    const float* xsrc = typ ? xb : xa;
    const u16* xsrcT = typ ? xbT : xaT;

#pragma unroll
    for (int rg = 0; rg < 4; ++rg) {
      int rowbase = base + rg * 16;
      if (rowbase < nrows) {   // nrows % 16 == 0: group fully valid or fully invalid
        int row = rowbase + r16;
        bf16x8 fA[4], fX[4];
        if constexpr (AGG) {
          const u16* ap = aggT + (size_t)(goff + row) * DF + kq * 8;
#pragma unroll
          for (int kk = 0; kk < 4; ++kk) fA[kk] = *(const bf16x8*)(ap + kk * 32);
        } else {
          const float* ap = outf + (size_t)(goff + row) * DF + kq * 8;
#pragma unroll
          for (int kk = 0; kk < 4; ++kk)
            fA[kk] = pack8(*(const float4*)(ap + kk * 32),
                           *(const float4*)(ap + kk * 32 + 4));
        }
        if constexpr (XT) {
          const u16* xp = xsrcT + (size_t)row * DF + kq * 8;
#pragma unroll
          for (int kk = 0; kk < 4; ++kk) fX[kk] = *(const bf16x8*)(xp + kk * 32);
        } else {
          const float* xp = xsrc + (size_t)row * DF + kq * 8;
#pragma unroll
          for (int kk = 0; kk < 4; ++kk)
            fX[kk] = pack8(*(const float4*)(xp + kk * 32),
                           *(const float4*)(xp + kk * 32 + 4));
        }

        f32x4 accW[2], accR[2];
#pragma unroll
        for (int ti = 0; ti < 2; ++ti) {
#pragma unroll
          for (int r = 0; r < 4; ++r) { accW[ti][r] = 0.f; accR[ti][r] = 0.f; }
        }
#pragma unroll
        for (int kk = 0; kk < 4; ++kk) {
#pragma unroll
          for (int ti = 0; ti < 2; ++ti) {
            accW[ti] = __builtin_amdgcn_mfma_f32_16x16x32_bf16(fA[kk], wf[ti][kk], accW[ti], 0, 0, 0);
            accR[ti] = __builtin_amdgcn_mfma_f32_16x16x32_bf16(fX[kk], wrf[ti][kk], accR[ti], 0, 0, 0);
          }
        }

        float cf[4];
#pragma unroll
        for (int r = 0; r < 4; ++r)
          cf[r] = (float)cnt[goff + rowbase + kq * 4 + r];

        // C/D layout: col = lane&15, row = (lane>>4)*4 + reg  [m89-verified]
#pragma unroll
        for (int ti = 0; ti < 2; ++ti) {
          int feat = (t0 + ti) * 16 + r16;
          float s = 0.f, q = 0.f;
#pragma unroll
          for (int r = 0; r < 4; ++r) {
            int grow = rowbase + kq * 4 + r;
            float g = accW[ti][r] + cf[r] * bvv[ti] + fmaxf(accR[ti][r] + brr[ti], 0.f);
            outf[(size_t)(goff + grow) * DF + feat] = g;
            s += g; q += g * g;
          }
          if (typ == 0) { sA[ti] += s; qA[ti] += q; }
          else          { sB[ti] += s; qB[ti] += q; }
        }
      }
    }
  }

  // BN partials: reduce over kq, then bucketed global atomics
  int bkt = blockIdx.x & (NBUCK - 1);
#pragma unroll
  for (int ti = 0; ti < 2; ++ti) {
    float s0 = sA[ti], q0 = qA[ti], s1 = sB[ti], q1 = qB[ti];
    s0 += __shfl_xor(s0, 16); q0 += __shfl_xor(q0, 16);
    s1 += __shfl_xor(s1, 16); q1 += __shfl_xor(q1, 16);
    s0 += __shfl_xor(s0, 32); q0 += __shfl_xor(q0, 32);
    s1 += __shfl_xor(s1, 32); q1 += __shfl_xor(q1, 32);
    if (kq == 0) {
      int feat = (t0 + ti) * 16 + r16;
      float* p = stats + (size_t)bkt * 4 * DF;
      atomicAdd(p + 0 * DF + feat, s0);
      atomicAdd(p + 1 * DF + feat, q0);
      atomicAdd(p + 2 * DF + feat, s1);
      atomicAdd(p + 3 * DF + feat, q1);
    }
  }
}

// ---- finalize stats ----
__global__ void k_stats(const float* __restrict__ stats,
                        const float* __restrict__ ga, const float* __restrict__ bea,
                        const float* __restrict__ gb, const float* __restrict__ beb,
                        float* __restrict__ scale, float* __restrict__ shift) {
  int tid = threadIdx.x;
  if (tid < 2 * DF) {
    int t = tid >> 7, f = tid & (DF - 1);
    float S = 0.f, SS = 0.f;
    for (int bk = 0; bk < NBUCK; ++bk) {
      const float* p = stats + (size_t)bk * 4 * DF;
      S  += p[(2 * t) * DF + f];
      SS += p[(2 * t + 1) * DF + f];
    }
    float n = t ? (float)NBONDS : (float)NATOMS;
    float mean = S / n;
    float var = SS / n - mean * mean;
    float rstd = rsqrtf(var + EPS);
    float g = t ? gb[f] : ga[f];
    float be = t ? beb[f] : bea[f];
    scale[tid] = rstd * g;
    shift[tid] = be - mean * rstd * g;
  }
}

// ---- in-place normalize (fp32) ----
__global__ void k_norm(float* __restrict__ out, const float* __restrict__ scale,
                       const float* __restrict__ shift) {
  const size_t nv = (size_t)NSEG * DF / 4;
  size_t stride = (size_t)gridDim.x * blockDim.x;
  for (size_t i = (size_t)blockIdx.x * blockDim.x + threadIdx.x; i < nv; i += stride) {
    size_t e = i * 4;
    int t = e >= (size_t)NATOMS * DF;
    int f = (int)(e & (DF - 1));
    const float* sc = scale + t * DF + f;
    const float* sh = shift + t * DF + f;
    float4 v = ((float4*)out)[i];
    v.x = fmaf(v.x, sc[0], sh[0]);
    v.y = fmaf(v.y, sc[1], sh[1]);
    v.z = fmaf(v.z, sc[2], sh[2]);
    v.w = fmaf(v.w, sc[3], sh[3]);
    ((float4*)out)[i] = v;
  }
}

extern "C" void kernel_launch(void* const* d_in, const int* in_sizes, int n_in,
                              void* d_out, int out_size, void* d_ws, size_t ws_size,
                              hipStream_t stream) {
  const float* xa  = (const float*)d_in[0];
  const float* xb  = (const float*)d_in[1];
  const int*   ab  = (const int*)d_in[2];
  const int*   ba  = (const int*)d_in[3];
  const float* W   = (const float*)d_in[4];
  const float* b   = (const float*)d_in[5];
  const float* Wr  = (const float*)d_in[6];
  const float* br  = (const float*)d_in[7];
  const float* ga  = (const float*)d_in[8];
  const float* bea = (const float*)d_in[9];
  const float* gb  = (const float*)d_in[10];
  const float* beb = (const float*)d_in[11];
  float* out = (float*)d_out;

  char* ws = (char*)d_ws;
  int*   cnt    = (int*)ws;                       // 2,000,000
  int*   off    = (int*)(ws +  2000000);          // 2,000,000
  int*   cursor = (int*)(ws +  4000000);          // 2,000,000
  int*   sorted = (int*)(ws +  6000000);          // 4,800,000
  float* stats  = (float*)(ws + 10800000);        // 65,536
  int*   bsum   = (int*)(ws + 10865536);          // 1,024
  int*   bbase  = (int*)(ws + 10866560);          // 1,024
  u16*   Wbf    = (u16*)(ws + 10867584);          // 32,768
  u16*   Wrbf   = (u16*)(ws + 10900352);          // 32,768
  float* scale  = (float*)(ws + 10933120);        // 1,024
  float* shift  = (float*)(ws + 10934144);        // 1,024
  // tiered buffers
  u16*   aggT = (u16*)(ws + 10935168);            // 128,000,000 -> ends 138,935,168
  u16*   xaT  = (u16*)(ws + 138935168);           //  51,200,000 -> ends 190,135,168
  u16*   xbT  = (u16*)(ws + 190135168);           //  76,800,000 -> ends 266,935,168
  const bool agg = ws_size >= 138935168ull;
  const bool xt  = ws_size >= 266935168ull;

  hipMemsetAsync(cnt, 0, 2000000, stream);
  hipMemsetAsync(stats, 0, 65536, stream);

  k_prep<<<64, 256, 0, stream>>>(W, Wr, Wbf, Wrbf);
  if (xt) {
    k_conv<<<2048, 256, 0, stream>>>(xa, xaT, NATOMS * DF / 8);
    k_conv<<<2048, 256, 0, stream>>>(xb, xbT, NBONDS * DF / 8);
  }
  k_hist<<<2048, 256, 0, stream>>>(ab, ba, cnt);
  k_scanA<<<NSBLK, 256, 0, stream>>>(cnt, bsum);
  k_scanB<<<1, 256, 0, stream>>>(bsum, bbase);
  k_scanC<<<NSBLK, 256, 0, stream>>>(cnt, bbase, off, cursor);
  k_fill<<<2048, 256, 0, stream>>>(ab, ba, cursor, sorted);

  if (xt) {
    k_gather<1, 1><<<4096, 256, 0, stream>>>(xa, xb, xaT, xbT, sorted, off, cnt, out, aggT);
    k_gemm<1, 1><<<2048, 256, 0, stream>>>(xa, xb, xaT, xbT, aggT, out, cnt,
                                           Wbf, Wrbf, b, br, stats);
  } else if (agg) {
    k_gather<1, 0><<<4096, 256, 0, stream>>>(xa, xb, xaT, xbT, sorted, off, cnt, out, aggT);
    k_gemm<1, 0><<<2048, 256, 0, stream>>>(xa, xb, xaT, xbT, aggT, out, cnt,
                                           Wbf, Wrbf, b, br, stats);
  } else {
    k_gather<0, 0><<<4096, 256, 0, stream>>>(xa, xb, xaT, xbT, sorted, off, cnt, out, aggT);
    k_gemm<0, 0><<<2048, 256, 0, stream>>>(xa, xb, xaT, xbT, aggT, out, cnt,
                                           Wbf, Wrbf, b, br, stats);
  }
  k_stats<<<1, 256, 0, stream>>>(stats, ga, bea, gb, beb, scale, shift);
  k_norm<<<8192, 256, 0, stream>>>(out, scale, shift);
}